// Round 12
// baseline (53.234 us; speedup 1.0000x reference)
//
#include <hip/hip_runtime.h>
#include <hip/hip_bf16.h>

typedef __attribute__((ext_vector_type(8)))  short bf16x8;
typedef __attribute__((ext_vector_type(16))) float f32x16;

#define I_N 256
#define T_N 256
#define L_N 32
#define E_N 128
#define P_N 49

// ---- pre-pass: pack text(B) + image(A) into 32x32x16 MFMA fragment order ----
// B frag [t*8+ks][lane][8]: col l = lane&31 (token), k = ks*16 + (lane>>5)*8 + j
// A frag [i*16 + pt*8 + ks][lane][8]: patch = pt*32 + (lane&31), same k map.
__global__ __launch_bounds__(256) void pack_all(const float* __restrict__ txt,
                                                const float* __restrict__ img,
                                                unsigned short* __restrict__ bpre,
                                                unsigned short* __restrict__ apre) {
    const int bid = blockIdx.x;
    if (bid < 512) {                                 // ---- text
        int gid  = bid * 256 + threadIdx.x;
        int lane = gid & 63;
        int ks   = (gid >> 6) & 7;
        int t    = gid >> 9;
        int l    = lane & 31;
        int e0   = ks * 16 + (lane >> 5) * 8;
        const float* src = txt + (t * L_N + l) * E_N + e0;
        union { unsigned short u[8]; bf16x8 v; } o;
        #pragma unroll
        for (int j = 0; j < 8; ++j) {
            __hip_bfloat16 h = __float2bfloat16(src[j]);
            o.u[j] = *reinterpret_cast<unsigned short*>(&h);
        }
        ((bf16x8*)bpre)[gid] = o.v;
    } else {                                         // ---- image
        int gid   = (bid - 512) * 256 + threadIdx.x;
        int lane  = gid & 63;
        int ks    = (gid >> 6) & 7;
        int pt    = (gid >> 9) & 1;
        int i     = gid >> 10;
        int patch = pt * 32 + (lane & 31);
        int e0    = ks * 16 + (lane >> 5) * 8;
        const float* src = img + i * (E_N * P_N) + e0 * P_N + patch;
        union { unsigned short u[8]; bf16x8 v; } o;
        #pragma unroll
        for (int j = 0; j < 8; ++j) {
            float x = (patch < P_N) ? src[j * P_N] : 0.0f;
            __hip_bfloat16 h = __float2bfloat16(x);
            o.u[j] = *reinterpret_cast<unsigned short*>(&h);
        }
        ((bf16x8*)apre)[gid] = o.v;
    }
}

// ---- main kernel: grid 512, 4 waves/block, XCD-ALIGNED TEXT GROUPS. ----
// Block b: tg=b%8 -> texts [tg*32, +32); ig=b/8 -> images ig*4+wid. Dispatch
// round-robins b over XCDs, so all 64 blocks sharing a text-group live on ONE
// XCD: per-XCD L2 fetches only 256KB of bpre (kills the 8x HBM refetch).
// Depth-2 register prefetch: bfX refilled for t+2 right after its MFMAs,
// issue-to-use cover ~1.5 text bodies >= HBM miss latency.
__global__ __launch_bounds__(256, 2) void clip_mfma(
    const unsigned short* __restrict__ apre,
    const unsigned short* __restrict__ bpre,
    const int*   __restrict__ tlen,
    const float* __restrict__ nlt,
    float*       __restrict__ out) {

    const int wid  = threadIdx.x >> 6;
    const int lane = threadIdx.x & 63;
    const int b    = blockIdx.x;           // 0..511
    const int t0   = (b & 7) * 32;         // text group (XCD-aligned)
    const int i    = (b >> 3) * 4 + wid;   // image
    const float scale = expf(nlt[0]);
    const bool  lo32  = (lane < 32);

    // Pin image A-frags: 2 patch-tiles x 8 k-steps = 64 VGPRs, reused for 32 texts.
    bf16x8 af[2][8];
    const bf16x8* ap = (const bf16x8*)apre + (size_t)i * 16 * 64;
    #pragma unroll
    for (int pt = 0; pt < 2; ++pt)
        #pragma unroll
        for (int ks = 0; ks < 8; ++ks)
            af[pt][ks] = ap[(pt * 8 + ks) * 64 + lane];

    const bf16x8* bp = (const bf16x8*)bpre;

    auto loadB = [&](bf16x8 (&bf)[8], int t) {
        const bf16x8* tb = bp + (size_t)t * 8 * 64;
        #pragma unroll
        for (int ks = 0; ks < 8; ++ks)
            bf[ks] = tb[ks * 64 + lane];
    };

    auto mfmaT = [&](f32x16& a0, f32x16& a1, bf16x8 (&bf)[8]) {
        #pragma unroll
        for (int rr = 0; rr < 16; ++rr) { a0[rr] = 0.0f; a1[rr] = 0.0f; }
        #pragma unroll
        for (int ks = 0; ks < 8; ++ks) {
            a0 = __builtin_amdgcn_mfma_f32_32x32x16_bf16(af[0][ks], bf[ks], a0, 0, 0, 0);
            a1 = __builtin_amdgcn_mfma_f32_32x32x16_bf16(af[1][ks], bf[ks], a1, 0, 0, 0);
        }
    };

    // Reduce: max over 49 patches, sum over 32 tokens.
    // C: col = lane&31 (token), row = (reg&3)+8*(reg>>2)+4*(lane>>5).
    // Tile1: regs 0..7 valid both halves; reg 8 lo-half only (patch 48).
    auto reduceT = [&](f32x16& c0, f32x16& c1, int t) {
        float m = c0[0];
        #pragma unroll
        for (int rr = 1; rr < 16; ++rr) m = fmaxf(m, c0[rr]);
        #pragma unroll
        for (int rr = 0; rr < 8; ++rr)  m = fmaxf(m, c1[rr]);
        m = fmaxf(m, lo32 ? c1[8] : -INFINITY);
        m = fmaxf(m, __shfl_xor(m, 32));            // merge halves -> 49-patch max
        float s = m;
        #pragma unroll
        for (int off = 1; off <= 16; off <<= 1)
            s += __shfl_xor(s, off);                // sum over 32 token cols
        if (lane == 0) {
            float match = (s / (float)tlen[t]) * scale;
            out[i * T_N + t]             = match;   // logits_per_image [I][T]
            out[I_N * T_N + t * I_N + i] = match;   // logits_per_text  [T][I]
        }
    };

    bf16x8 bfA[8], bfB[8];
    f32x16 aA0, aA1, aB0, aB1;

    loadB(bfA, t0);
    loadB(bfB, t0 + 1);

    #pragma unroll 1
    for (int k = 0; k < 32; k += 2) {
        mfmaT(aA0, aA1, bfA);                       // consume bfA (text t0+k)
        if (k + 2 < 32) loadB(bfA, t0 + k + 2);     // refill: ~1.5 bodies of cover
        reduceT(aA0, aA1, t0 + k);                  // hides under bfB's MFMAs? no:
                                                    //   hides under other wave; cheap
        mfmaT(aB0, aB1, bfB);                       // consume bfB (text t0+k+1)
        if (k + 3 < 32) loadB(bfB, t0 + k + 3);
        reduceT(aB0, aB1, t0 + k + 1);
    }
}

extern "C" void kernel_launch(void* const* d_in, const int* in_sizes, int n_in,
                              void* d_out, int out_size, void* d_ws, size_t ws_size,
                              hipStream_t stream) {
    const float* img  = (const float*)d_in[0];
    const float* txt  = (const float*)d_in[1];
    const int*   tlen = (const int*)d_in[2];
    const float* nlt  = (const float*)d_in[3];
    float*       out  = (float*)d_out;

    unsigned short* bpre = (unsigned short*)d_ws;                       // 2 MB
    unsigned short* apre = (unsigned short*)((char*)d_ws + (2u << 20)); // 4 MB

    pack_all<<<1536, 256, 0, stream>>>(txt, img, bpre, apre);
    clip_mfma<<<512, 256, 0, stream>>>(apre, bpre, tlen, nlt, out);
}

// Round 14
// 45.508 us; speedup vs baseline: 1.1698x; 1.1698x over previous
//
#include <hip/hip_runtime.h>
#include <hip/hip_bf16.h>

typedef __attribute__((ext_vector_type(8)))  short bf16x8;
typedef __attribute__((ext_vector_type(16))) float f32x16;
typedef __attribute__((ext_vector_type(4)))  float f32x4;

#define I_N 256
#define T_N 256
#define L_N 32
#define E_N 128
#define P_N 49
#define SSTR 36   // smax dword stride: 144B rows -> 16B-aligned float4 reads

// ---- pre-pass: pack text(B) + image(A) into 32x32x16 MFMA fragment order ----
// B frag [t*8+ks][lane][8]: col l = lane&31 (token), k = ks*16 + (lane>>5)*8 + j
// A frag [i*16 + pt*8 + ks][lane][8]: patch = pt*32 + (lane&31), same k map.
__global__ __launch_bounds__(256) void pack_all(const float* __restrict__ txt,
                                                const float* __restrict__ img,
                                                unsigned short* __restrict__ bpre,
                                                unsigned short* __restrict__ apre) {
    const int bid = blockIdx.x;
    if (bid < 512) {                                 // ---- text
        int gid  = bid * 256 + threadIdx.x;
        int lane = gid & 63;
        int ks   = (gid >> 6) & 7;
        int t    = gid >> 9;
        int l    = lane & 31;
        int e0   = ks * 16 + (lane >> 5) * 8;
        const float* src = txt + (t * L_N + l) * E_N + e0;
        union { unsigned short u[8]; bf16x8 v; } o;
        #pragma unroll
        for (int j = 0; j < 8; ++j) {
            __hip_bfloat16 h = __float2bfloat16(src[j]);
            o.u[j] = *reinterpret_cast<unsigned short*>(&h);
        }
        ((bf16x8*)bpre)[gid] = o.v;
    } else {                                         // ---- image
        int gid   = (bid - 512) * 256 + threadIdx.x;
        int lane  = gid & 63;
        int ks    = (gid >> 6) & 7;
        int pt    = (gid >> 9) & 1;
        int i     = gid >> 10;
        int patch = pt * 32 + (lane & 31);
        int e0    = ks * 16 + (lane >> 5) * 8;
        const float* src = img + i * (E_N * P_N) + e0 * P_N + patch;
        union { unsigned short u[8]; bf16x8 v; } o;
        #pragma unroll
        for (int j = 0; j < 8; ++j) {
            float x = (patch < P_N) ? src[j * P_N] : 0.0f;
            __hip_bfloat16 h = __float2bfloat16(x);
            o.u[j] = *reinterpret_cast<unsigned short*>(&h);
        }
        ((bf16x8*)apre)[gid] = o.v;
    }
}

// ---- main kernel: grid 512 (2/CU), 4 waves/block, no barriers. ----
// Per text: 16 MFMA (first of each chain consumes constant ZERO -> no acc-zero
// movs) + ~13 max3-friendly fmax + 1 shfl + 1 ds_write to WAVE-PRIVATE smax.
// Cross-lane token-sum deferred: once per wave after all 32 texts.
__global__ __launch_bounds__(256, 2) void clip_mfma(
    const unsigned short* __restrict__ apre,
    const unsigned short* __restrict__ bpre,
    const int*   __restrict__ tlen,
    const float* __restrict__ nlt,
    float*       __restrict__ out) {

    __shared__ __align__(16) float smax[4][32 * SSTR];   // 18 KB/block

    const int wid  = threadIdx.x >> 6;
    const int lane = threadIdx.x & 63;
    const int b    = blockIdx.x;           // 0..511
    const int t0   = (b & 7) * 32;         // text group of 32
    const int i    = (b >> 3) * 4 + wid;   // image
    const float scale = expf(nlt[0]);
    const bool  lo32  = (lane < 32);

    // Pin image A-frags: 2 patch-tiles x 8 k-steps = 64 VGPRs.
    bf16x8 af[2][8];
    const bf16x8* ap = (const bf16x8*)apre + (size_t)i * 16 * 64;
    #pragma unroll
    for (int pt = 0; pt < 2; ++pt)
        #pragma unroll
        for (int ks = 0; ks < 8; ++ks)
            af[pt][ks] = ap[(pt * 8 + ks) * 64 + lane];

    f32x16 ZERO;
    #pragma unroll
    for (int rr = 0; rr < 16; ++rr) ZERO[rr] = 0.0f;

    const bf16x8* bp = (const bf16x8*)bpre;

    auto loadB = [&](bf16x8 (&bf)[8], int t) {
        const bf16x8* tb = bp + (size_t)t * 8 * 64;
        #pragma unroll
        for (int ks = 0; ks < 8; ++ks)
            bf[ks] = tb[ks * 64 + lane];
    };

    auto mfmaT = [&](f32x16& a0, f32x16& a1, bf16x8 (&bf)[8]) {
        a0 = __builtin_amdgcn_mfma_f32_32x32x16_bf16(af[0][0], bf[0], ZERO, 0, 0, 0);
        a1 = __builtin_amdgcn_mfma_f32_32x32x16_bf16(af[1][0], bf[0], ZERO, 0, 0, 0);
        #pragma unroll
        for (int ks = 1; ks < 8; ++ks) {
            a0 = __builtin_amdgcn_mfma_f32_32x32x16_bf16(af[0][ks], bf[ks], a0, 0, 0, 0);
            a1 = __builtin_amdgcn_mfma_f32_32x32x16_bf16(af[1][ks], bf[ks], a1, 0, 0, 0);
        }
    };

    // Per-text: patch-max (max3-friendly triples) + half-merge + private ds_write.
    // C: col = lane&31 (token), row = (reg&3)+8*(reg>>2)+4*(lane>>5).
    // Tile1: regs 0..7 valid both halves; reg 8 lo-half only (patch 48).
    auto maxStore = [&](f32x16& c0, f32x16& c1, int tloc) {
        float x0 = fmaxf(fmaxf(c0[0],  c0[1]),  c0[2]);
        float x1 = fmaxf(fmaxf(c0[3],  c0[4]),  c0[5]);
        float x2 = fmaxf(fmaxf(c0[6],  c0[7]),  c0[8]);
        float x3 = fmaxf(fmaxf(c0[9],  c0[10]), c0[11]);
        float x4 = fmaxf(fmaxf(c0[12], c0[13]), c0[14]);
        float x5 = fmaxf(fmaxf(c0[15], c1[0]),  c1[1]);
        float x6 = fmaxf(fmaxf(c1[2],  c1[3]),  c1[4]);
        float x7 = fmaxf(fmaxf(c1[5],  c1[6]),  c1[7]);
        float y0 = fmaxf(fmaxf(x0, x1), x2);
        float y1 = fmaxf(fmaxf(x3, x4), x5);
        float y2 = fmaxf(fmaxf(x6, x7), lo32 ? c1[8] : c1[7]);  // p48 lo-half only
        float m  = fmaxf(fmaxf(y0, y1), y2);
        m = fmaxf(m, __shfl_xor(m, 32));     // merge halves -> 49-patch max
        if (lane < 32) smax[wid][tloc * SSTR + lane] = m;   // conflict-free
    };

    bf16x8 bfA[8], bfB[8];
    f32x16 aA0, aA1, aB0, aB1;

    loadB(bfA, t0);
    loadB(bfB, t0 + 1);

    #pragma unroll 1
    for (int k = 0; k < 32; k += 2) {
        mfmaT(aA0, aA1, bfA);
        if (k + 2 < 32) loadB(bfA, t0 + k + 2);
        maxStore(aA0, aA1, k);
        mfmaT(aB0, aB1, bfB);
        if (k + 3 < 32) loadB(bfB, t0 + k + 3);
        maxStore(aB0, aB1, k + 1);
    }

    // Same-wave LDS readback: drain ds queue, pin ordering.
    asm volatile("s_waitcnt lgkmcnt(0)" ::: "memory");
    __builtin_amdgcn_sched_barrier(0);

    // Final token-sum: 2 lanes per text, 16 floats each, once per wave.
    const int p = lane >> 1, h = lane & 1;
    const f32x4* rp = (const f32x4*)&smax[wid][p * SSTR + h * 16];
    f32x4 v0 = rp[0], v1 = rp[1], v2 = rp[2], v3 = rp[3];
    float s = (((v0[0] + v0[1]) + (v0[2] + v0[3])) + ((v1[0] + v1[1]) + (v1[2] + v1[3])))
            + (((v2[0] + v2[1]) + (v2[2] + v2[3])) + ((v3[0] + v3[1]) + (v3[2] + v3[3])));
    s += __shfl_xor(s, 1);                   // join the two half-sums
    const int t = t0 + p;
    const float match = (s / (float)tlen[t]) * scale;
    if (h == 0) out[i * T_N + t]             = match;   // logits_per_image [I][T]
    else        out[I_N * T_N + t * I_N + i] = match;   // logits_per_text  [T][I]
}

extern "C" void kernel_launch(void* const* d_in, const int* in_sizes, int n_in,
                              void* d_out, int out_size, void* d_ws, size_t ws_size,
                              hipStream_t stream) {
    const float* img  = (const float*)d_in[0];
    const float* txt  = (const float*)d_in[1];
    const int*   tlen = (const int*)d_in[2];
    const float* nlt  = (const float*)d_in[3];
    float*       out  = (float*)d_out;

    unsigned short* bpre = (unsigned short*)d_ws;                       // 2 MB
    unsigned short* apre = (unsigned short*)((char*)d_ws + (2u << 20)); // 4 MB

    pack_all<<<1536, 256, 0, stream>>>(txt, img, bpre, apre);
    clip_mfma<<<512, 256, 0, stream>>>(apre, bpre, tlen, nlt, out);
}